// Round 3
// baseline (103.560 us; speedup 1.0000x reference)
//
#include <hip/hip_runtime.h>
#include <math.h>

#define TPB 256
#define JCHUNK 128

// Pairwise MarginRankingLoss, triangular (j>i) only — the hinge
// h(i,j) = max(0, -sign(t_i-t_j)*(p_i-p_j) + 0.1) is i<->j symmetric, so
// sum/count over j>i equals the reference. Masked / |dt|<eps / OOB pairs are
// killed by a NaN sentinel in the staged target (all compares w/ NaN false).
//
// Single fused kernel: each active tile reduces to one (sum,count) pair,
// atomicAdd's (double, device scope) into d_ws, and the LAST tile to finish
// (completion counter) computes sum/count and writes d_out.
// d_ws layout: [0..7] sum (double), [8..15] cnt (double), [16..19] ctr (uint)
// — zeroed by a hipMemsetAsync before launch.
__global__ __launch_bounds__(TPB) void mrl_fused(
    const float* __restrict__ p, const float* __restrict__ t,
    const int* __restrict__ m, int B, int n_active,
    double* __restrict__ acc_ws, float* __restrict__ out)
{
    const int i0 = blockIdx.x * TPB;
    const int j0 = blockIdx.y * JCHUNK;

    // no pair (i,j) with j>i in this tile -> nothing to contribute
    if (j0 + JCHUNK - 1 <= i0) return;

    __shared__ float2 sj[JCHUNK];          // (p_j, t_j) ; t_j = NaN if masked/OOB

    if (threadIdx.x < JCHUNK) {
        const int j = j0 + threadIdx.x;
        const bool ok = (j < B);
        float pj = ok ? p[j] : 0.0f;
        float tj = (ok && m[j]) ? t[j] : __builtin_nanf("");
        sj[threadIdx.x] = make_float2(pj, tj);
    }
    __syncthreads();

    const int i = i0 + threadIdx.x;
    float pi = 0.0f, ti = __builtin_nanf("");
    if (i < B) {
        pi = p[i];
        ti = m[i] ? t[i] : __builtin_nanf("");
    }

    float acc = 0.0f, cnt = 0.0f;
    const bool diag = (j0 < i0 + TPB);     // tile straddles the diagonal

    if (!diag) {
        #pragma unroll 8
        for (int k = 0; k < JCHUNK; ++k) {
            const float2 pt = sj[k];
            const float dt = ti - pt.y;
            const float q  = pt.x - pi;                    // q = -(p_i - p_j)
            const bool  v  = fabsf(dt) >= 1e-6f;           // false on NaN
            const float cs = copysignf(1.0f, dt);          // v_bfi
            const float h  = fmaxf(fmaf(cs, q, 0.1f), 0.0f);
            acc += v ? h : 0.0f;
            cnt += v ? 1.0f : 0.0f;
        }
    } else {
        #pragma unroll 8
        for (int k = 0; k < JCHUNK; ++k) {
            const float2 pt = sj[k];
            const int   j  = j0 + k;
            const float dt = ti - pt.y;
            const float q  = pt.x - pi;
            const bool  v  = (fabsf(dt) >= 1e-6f) && (j > i);
            const float cs = copysignf(1.0f, dt);
            const float h  = fmaxf(fmaf(cs, q, 0.1f), 0.0f);
            acc += v ? h : 0.0f;
            cnt += v ? 1.0f : 0.0f;
        }
    }

    // block reduction: wave shuffle then cross-wave via LDS
    #pragma unroll
    for (int off = 32; off > 0; off >>= 1) {
        acc += __shfl_down(acc, off, 64);
        cnt += __shfl_down(cnt, off, 64);
    }
    __shared__ float wsum[TPB / 64];
    __shared__ float wcnt[TPB / 64];
    const int lane = threadIdx.x & 63;
    const int wid  = threadIdx.x >> 6;
    if (lane == 0) { wsum[wid] = acc; wcnt[wid] = cnt; }
    __syncthreads();

    if (threadIdx.x == 0) {
        float a = 0.0f, c = 0.0f;
        #pragma unroll
        for (int w = 0; w < TPB / 64; ++w) { a += wsum[w]; c += wcnt[w]; }

        atomicAdd(&acc_ws[0], (double)a);
        atomicAdd(&acc_ws[1], (double)c);
        __threadfence();                                   // publish before ticket
        unsigned* ctr = (unsigned*)&acc_ws[2];
        const unsigned old = atomicAdd(ctr, 1u);
        if (old == (unsigned)(n_active - 1)) {
            // all contributions visible; atomic read-modify-write w/ 0 = load
            const double S = atomicAdd(&acc_ws[0], 0.0);
            const double C = atomicAdd(&acc_ws[1], 0.0);
            out[0] = (float)(S / fmax(C, 1.0));
        }
    }
}

extern "C" void kernel_launch(void* const* d_in, const int* in_sizes, int n_in,
                              void* d_out, int out_size, void* d_ws, size_t ws_size,
                              hipStream_t stream)
{
    const float* p = (const float*)d_in[0];
    const float* t = (const float*)d_in[1];
    const int*   m = (const int*)d_in[2];
    const int B = in_sizes[0];

    const int iblocks = (B + TPB - 1) / TPB;
    const int jchunks = (B + JCHUNK - 1) / JCHUNK;

    // count tiles that actually contribute (skip: j0 + JCHUNK - 1 <= i0)
    int n_active = 0;
    for (int bi = 0; bi < iblocks; ++bi) {
        const int i0 = bi * TPB;
        for (int bj = 0; bj < jchunks; ++bj) {
            if (bj * JCHUNK + JCHUNK - 1 > i0) { ++n_active; break_hint: ; }
        }
    }
    // (loop above counts first active bj then falls through; recount exactly)
    n_active = 0;
    for (int bi = 0; bi < iblocks; ++bi) {
        const int i0 = bi * TPB;
        const int skipped = (i0 >= JCHUNK - 1) ? ((i0 - (JCHUNK - 1)) / JCHUNK + 1) : 0;
        n_active += jchunks - (skipped < jchunks ? skipped : jchunks);
    }

    hipMemsetAsync(d_ws, 0, 24, stream);   // sum, cnt (doubles) + ctr (uint)

    dim3 grid(iblocks, jchunks);
    mrl_fused<<<grid, TPB, 0, stream>>>(p, t, m, B, n_active,
                                        (double*)d_ws, (float*)d_out);
}

// Round 4
// 71.820 us; speedup vs baseline: 1.4419x; 1.4419x over previous
//
#include <hip/hip_runtime.h>
#include <math.h>

#define TPB 256
#define JCHUNK 128

// Pairwise MarginRankingLoss, triangular (j>i) only — the hinge
// h(i,j) = max(0, -sign(t_i-t_j)*(p_i-p_j) + 0.1) is i<->j symmetric, so
// sum/count over j>i equals the reference ratio. Masked / |dt|<eps / OOB
// pairs are killed by a NaN sentinel in the staged target (all float
// compares with NaN are false).
//
// R4 notes: two-kernel structure (R3's fused single-address atomic tail cost
// ~38 µs of serialization — reverted). Count accumulates on the SCALAR pipe
// via popcount(ballot), dual-issued with VALU; partials stored as one float2.
__global__ __launch_bounds__(TPB) void mrl_partial(
    const float* __restrict__ p, const float* __restrict__ t,
    const int* __restrict__ m, int B,
    float2* __restrict__ part)
{
    const int i0  = blockIdx.x * TPB;
    const int j0  = blockIdx.y * JCHUNK;
    const int blk = blockIdx.y * gridDim.x + blockIdx.x;

    // no pair (i,j) with j>i in this tile -> zero partial, exit
    if (j0 + JCHUNK - 1 <= i0) {
        if (threadIdx.x == 0) part[blk] = make_float2(0.0f, 0.0f);
        return;
    }

    __shared__ float2 sj[JCHUNK];          // (p_j, t_j); t_j = NaN if masked/OOB

    if (threadIdx.x < JCHUNK) {
        const int j = j0 + threadIdx.x;
        const bool ok = (j < B);
        const float pj = ok ? p[j] : 0.0f;
        const float tj = (ok && m[j]) ? t[j] : __builtin_nanf("");
        sj[threadIdx.x] = make_float2(pj, tj);
    }
    __syncthreads();

    const int i = i0 + threadIdx.x;
    float pi = 0.0f, ti = __builtin_nanf("");
    if (i < B) {
        pi = p[i];
        ti = m[i] ? t[i] : __builtin_nanf("");
    }

    float acc = 0.0f;
    unsigned cnt = 0;                      // wave-uniform (SALU) pair count
    const bool diag = (j0 < i0 + TPB);     // tile straddles the diagonal

    if (!diag) {
        // entirely above diagonal: every j > every i, no index predicate
        #pragma unroll 8
        for (int k = 0; k < JCHUNK; ++k) {
            const float2 pt = sj[k];
            const float dt = ti - pt.y;
            const float q  = pt.x - pi;                    // -(p_i - p_j)
            const bool  v  = fabsf(dt) >= 1e-6f;           // false on NaN
            const float h  = fmaxf(fmaf(copysignf(1.0f, dt), q, 0.1f), 0.0f);
            acc += v ? h : 0.0f;
            cnt += (unsigned)__popcll(__ballot(v));        // scalar pipe
        }
    } else {
        #pragma unroll 8
        for (int k = 0; k < JCHUNK; ++k) {
            const float2 pt = sj[k];
            const int   j  = j0 + k;
            const float dt = ti - pt.y;
            const float q  = pt.x - pi;
            const bool  v  = (fabsf(dt) >= 1e-6f) && (j > i);
            const float h  = fmaxf(fmaf(copysignf(1.0f, dt), q, 0.1f), 0.0f);
            acc += v ? h : 0.0f;
            cnt += (unsigned)__popcll(__ballot(v));
        }
    }

    // sum: wave shuffle reduce; cnt is already wave-uniform (no shuffles)
    #pragma unroll
    for (int off = 32; off > 0; off >>= 1)
        acc += __shfl_down(acc, off, 64);

    __shared__ float wsum[TPB / 64];
    __shared__ float wcnt[TPB / 64];
    const int lane = threadIdx.x & 63;
    const int wid  = threadIdx.x >> 6;
    if (lane == 0) { wsum[wid] = acc; wcnt[wid] = (float)cnt; }
    __syncthreads();
    if (threadIdx.x == 0) {
        float a = 0.0f, c = 0.0f;
        #pragma unroll
        for (int w = 0; w < TPB / 64; ++w) { a += wsum[w]; c += wcnt[w]; }
        part[blk] = make_float2(a, c);
    }
}

// Stage 2: single block reduces all per-block partials in double and divides.
__global__ __launch_bounds__(256) void mrl_final(
    const float2* __restrict__ part, int nblk, float* __restrict__ out)
{
    double a = 0.0, c = 0.0;
    for (int k = threadIdx.x; k < nblk; k += 256) {
        const float2 v = part[k];
        a += (double)v.x;
        c += (double)v.y;
    }
    #pragma unroll
    for (int off = 32; off > 0; off >>= 1) {
        a += __shfl_down(a, off, 64);
        c += __shfl_down(c, off, 64);
    }
    __shared__ double sa[4];
    __shared__ double sc[4];
    const int lane = threadIdx.x & 63;
    const int wid  = threadIdx.x >> 6;
    if (lane == 0) { sa[wid] = a; sc[wid] = c; }
    __syncthreads();
    if (threadIdx.x == 0) {
        double A = 0.0, C = 0.0;
        #pragma unroll
        for (int w = 0; w < 4; ++w) { A += sa[w]; C += sc[w]; }
        out[0] = (float)(A / fmax(C, 1.0));
    }
}

extern "C" void kernel_launch(void* const* d_in, const int* in_sizes, int n_in,
                              void* d_out, int out_size, void* d_ws, size_t ws_size,
                              hipStream_t stream)
{
    const float* p = (const float*)d_in[0];
    const float* t = (const float*)d_in[1];
    const int*   m = (const int*)d_in[2];
    const int B = in_sizes[0];

    const int iblocks = (B + TPB - 1) / TPB;
    const int jchunks = (B + JCHUNK - 1) / JCHUNK;
    const int nblk = iblocks * jchunks;

    float2* part = (float2*)d_ws;

    dim3 grid(iblocks, jchunks);
    mrl_partial<<<grid, TPB, 0, stream>>>(p, t, m, B, part);
    mrl_final<<<1, 256, 0, stream>>>(part, nblk, (float*)d_out);
}